// Round 1
// baseline (273795.239 us; speedup 1.0000x reference)
//
#include <hip/hip_runtime.h>
#include <stdint.h>

#define DEV static __device__ __forceinline__

namespace {
constexpr int Bx = 16, ENCx = 512, DECx = 800, Dx = 256, Hx = 1024;
constexpr int NBLK = 256, NTHR = 512;

// ---- workspace layout (float offsets) ----
constexpr int WS_HBUF = 0;                    // 2 * B*H   (double-buffered h)
constexpr int WS_C    = WS_HBUF + 2*Bx*Hx;    // B*H
constexpr int WS_CTX  = WS_C    + Bx*Hx;      // B*D
constexpr int WS_NCTX = WS_CTX  + Bx*Dx;      // B*D
constexpr int WS_X1   = WS_NCTX + Bx*Dx;      // B*D
constexpr int WS_AL   = WS_X1   + Bx*Dx;      // B*ENC
constexpr int WS_LOC  = WS_AL   + Bx*ENCx;    // 16*8
constexpr int WS_POUT = WS_LOC  + 128;        // 16*32
constexpr int WS_FEND = WS_POUT + 16*32;
// ---- int area (int offsets, relative to wsf + WS_FEND) ----
constexpr int IW_F1  = 0;                         // flag1[DEC]     : x1 done (count to 32)
constexpr int IW_F2  = IW_F1 + DECx;              // flag2[DEC*16]  : align[b] done
constexpr int IW_PF  = IW_F2 + DECx*16;           // pairflag[DEC*16]: half1 partial-out done
constexpr int IW_BAR = ((IW_PF + DECx*16 + 63)/64)*64; // barrier: cnt at +0, gen at +32
constexpr int IW_END = IW_BAR + 64;
constexpr size_t CTXOUT = (size_t)Bx*DECx*Dx;     // weights output starts here
}

DEV float sigm(float x){ return 1.0f/(1.0f + __expf(-x)); }
DEV float ftanh(float x){
  x = fminf(fmaxf(x, -15.0f), 15.0f);
  float e = __expf(2.0f*x);
  return (e - 1.0f) / (e + 1.0f);
}
// reduce over the 16-lane k-group (lane bits 0..3): xor 1,2,4,8 are DPP-cheap
DEV float wred16(float v){
  v += __shfl_xor(v, 1); v += __shfl_xor(v, 2);
  v += __shfl_xor(v, 4); v += __shfl_xor(v, 8);
  return v;
}
DEV int  ld_acq(int* p){ return __hip_atomic_load(p, __ATOMIC_ACQUIRE, __HIP_MEMORY_SCOPE_AGENT); }
DEV void st_rel(int* p, int v){ __hip_atomic_store(p, v, __ATOMIC_RELEASE, __HIP_MEMORY_SCOPE_AGENT); }

DEV void block_wait(int* p, int target){
  if (threadIdx.x == 0){
    while (ld_acq(p) < target) __builtin_amdgcn_s_sleep(1);
  }
  __syncthreads();
  __threadfence();   // acquire: invalidate stale L1/L2 before reading producer data
}

DEV void gridbar(int* bar, unsigned &gen){
  __syncthreads();
  if (threadIdx.x == 0){
    __threadfence(); // release: write back my block's dirty lines
    unsigned old = (unsigned)__hip_atomic_fetch_add(bar, 1, __ATOMIC_ACQ_REL, __HIP_MEMORY_SCOPE_AGENT);
    if (old == (unsigned)(gridDim.x - 1)){
      __hip_atomic_store(bar, 0, __ATOMIC_RELAXED, __HIP_MEMORY_SCOPE_AGENT);
      __hip_atomic_store(bar + 32, (int)(gen + 1u), __ATOMIC_RELEASE, __HIP_MEMORY_SCOPE_AGENT);
    } else {
      while ((unsigned)ld_acq(bar + 32) == gen) __builtin_amdgcn_s_sleep(2);
    }
  }
  __syncthreads();
  __threadfence();   // acquire side for every thread
  gen++;
}

// one 64-element k-chunk for 2 gate rows x 4 batches (lane covers k = klane*4..+3)
DEV void gchunk(float (&acc)[2][4], float4 wa, float4 wb, const float* xlane, size_t xstride, int b4){
  #pragma unroll
  for (int bi = 0; bi < 4; ++bi){
    float4 xv = *reinterpret_cast<const float4*>(xlane + (size_t)(b4*4 + bi)*xstride);
    acc[0][bi] = fmaf(wa.x,xv.x, fmaf(wa.y,xv.y, fmaf(wa.z,xv.z, fmaf(wa.w,xv.w, acc[0][bi]))));
    acc[1][bi] = fmaf(wb.x,xv.x, fmaf(wb.y,xv.y, fmaf(wb.z,xv.z, fmaf(wb.w,xv.w, acc[1][bi]))));
  }
}

extern "C" __global__ void gmm_init(float* wsf){
  int* wsi = (int*)(wsf + WS_FEND);
  int idx = blockIdx.x*blockDim.x + threadIdx.x;
  for (int k = idx; k < IW_END; k += gridDim.x*blockDim.x) wsi[k] = 0;
  if (idx < 128) wsf[WS_LOC + idx] = -0.1f;   // loc init
}

extern "C" __global__ void __launch_bounds__(NTHR, 2) gmm_main(
    const float* __restrict__ enc, const float* __restrict__ mel,
    const int* __restrict__ outlen, const int* __restrict__ condlen,
    const float* __restrict__ Wih, const float* __restrict__ Whh,
    const float* __restrict__ bih, const float* __restrict__ bhh,
    const float* __restrict__ W1,  const float* __restrict__ b1v,
    const float* __restrict__ W2,  const float* __restrict__ Wlin,
    const float* __restrict__ blin,
    float* __restrict__ out, float* __restrict__ wsf)
{
  const int bk = blockIdx.x, tid = threadIdx.x;
  const int klane4 = (tid & 15) * 4;       // lane's k offset within a 64-el chunk
  const int b4 = (tid >> 4) & 3;           // which 4-batch group this lane owns
  const int wid = tid >> 6;                // wave id 0..7

  int* wsi   = (int*)(wsf + WS_FEND);
  int* flag1 = wsi + IW_F1;
  int* flag2 = wsi + IW_F2;
  int* pf    = wsi + IW_PF;
  int* bar   = wsi + IW_BAR;
  float* hb0    = wsf + WS_HBUF;
  float* cws    = wsf + WS_C;
  float* ctxws  = wsf + WS_CTX;
  float* nctxws = wsf + WS_NCTX;
  float* x1ws   = wsf + WS_X1;
  float* alws   = wsf + WS_AL;
  float* locws  = wsf + WS_LOC;
  float* pout   = wsf + WS_POUT;

  __shared__ float g_lds[256];            // [jidx 16][b 16]
  __shared__ float x2p[512];
  __shared__ float x2l[128];
  __shared__ float outl[32];
  __shared__ float mixw[8], mixlc[8], mixis[8];
  __shared__ float cpn[2][32][16];

  // gate-row ownership: every block owns u in [bk*4, bk*4+4), all 4 gates
  const int jidx0 = 2*wid;                               // wave covers jidx0, jidx0+1
  const int j0 = (jidx0 >> 2)*1024 + bk*4 + (jidx0 & 3); // jidx = gate*4 + ul
  const int j1 = ((jidx0+1) >> 2)*1024 + bk*4 + ((jidx0+1) & 3);
  const float* WihR0 = Wih + (size_t)j0*768;
  const float* WihR1 = Wih + (size_t)j1*768;
  const float* WhhR0 = Whh + (size_t)j0*1024;
  const float* WhhR1 = Whh + (size_t)j1*1024;

  const bool is_x1   = (bk < 32);                 // x1 rows d in [bk*8, bk*8+8)
  const bool is_head = (bk >= 32 && bk < 64);     // pair per batch
  const int  hbb  = (bk - 32) >> 1;
  const int  half = (bk - 32) & 1;

  // W2 half cached in registers (64 VGPRs): row = half*128 + (tid>>2), cols kq*64..+64
  float4 w2r[16];
  if (is_head){
    int rr = half*128 + (tid >> 2), kq = tid & 3;
    const float* w2row = W2 + (size_t)rr*256 + kq*64;
    #pragma unroll
    for (int i = 0; i < 16; ++i) w2r[i] = *reinterpret_cast<const float4*>(w2row + i*4);
  }

  auto ctx_slice = [&](int s, int t){
    // slice s: batch s>>4, dims [(s&15)*16 .. +16). Computes ctx & nctx (rolled align).
    int cb = s >> 4, d0 = (s & 15) * 16;
    int dl = tid & 15, eg = tid >> 4;
    int d = d0 + dl;
    const float* encb = enc + (size_t)cb*ENCx*Dx;
    const float* alb  = alws + cb*512;
    float ca = 0.f, na = 0.f;
    #pragma unroll
    for (int i = 0; i < 16; ++i){
      int e = eg*16 + i;
      float av = alb[e];
      float nv = alb[(e + 511) & 511];       // next_w[e] = align[e-1 mod 512]
      float ev = encb[(size_t)e*256 + d];
      ca = fmaf(av, ev, ca);
      na = fmaf(nv, ev, na);
    }
    cpn[0][eg][dl] = ca;
    cpn[1][eg][dl] = na;
    __syncthreads();
    if (tid < 32){
      int z = tid >> 4, dd = tid & 15;
      float sum = 0.f;
      #pragma unroll
      for (int g2 = 0; g2 < 32; ++g2) sum += cpn[z][g2][dd];
      if (z == 0){
        ctxws[cb*256 + d0 + dd] = sum;
        out[(size_t)cb*((size_t)DECx*Dx) + (size_t)t*Dx + d0 + dd] = sum; // align already vdec-masked
      } else {
        nctxws[cb*256 + d0 + dd] = sum;
      }
    }
    __syncthreads();
  };

  unsigned gen = 0;

  // ---------------- prologue: gates for t=0  (q = [mel0, 0, enc[:,0,:]], h=0, c=0)
  {
    float acc[2][4] = {{0,0,0,0},{0,0,0,0}};
    #pragma unroll
    for (int it = 0; it < 4; ++it){            // mel part (q cols 0..255)
      int k = it*64 + klane4;
      float4 wa = *(const float4*)(WihR0 + k), wb = *(const float4*)(WihR1 + k);
      gchunk(acc, wa, wb, mel + k, (size_t)DECx*Dx, b4);
    }
    #pragma unroll
    for (int it = 0; it < 4; ++it){            // nctx = enc[:,0,:] (q cols 512..767)
      int k = it*64 + klane4;
      float4 wa = *(const float4*)(WihR0 + 512 + k), wb = *(const float4*)(WihR1 + 512 + k);
      gchunk(acc, wa, wb, enc + k, (size_t)ENCx*Dx, b4);
    }
    #pragma unroll
    for (int jj = 0; jj < 2; ++jj)
      #pragma unroll
      for (int bi = 0; bi < 4; ++bi){
        float v = wred16(acc[jj][bi]);
        if ((tid & 15) == 0) g_lds[(jidx0 + jj)*16 + b4*4 + bi] = v;
      }
    __syncthreads();
    if (tid < 64){
      int b = tid & 15, ul = tid >> 4, u = bk*4 + ul;
      float gi = g_lds[( 0 + ul)*16 + b] + bih[u]        + bhh[u];
      float gg = g_lds[( 8 + ul)*16 + b] + bih[2048 + u] + bhh[2048 + u];
      float go = g_lds[(12 + ul)*16 + b] + bih[3072 + u] + bhh[3072 + u];
      float c2 = sigm(gi) * ftanh(gg);          // c_old = 0 (forget term drops)
      float h2 = sigm(go) * ftanh(c2);
      cws[b*1024 + u] = c2;
      hb0[b*1024 + u] = h2;                     // h_buf[0] = h_0
    }
  }
  gridbar(bar, gen);

  // ---------------- main loop ----------------
  for (int t = 0; t < DECx; ++t){
    const float* hcur = hb0 + (t & 1)*Bx*Hx;
    float*       hnxt = hb0 + ((t + 1) & 1)*Bx*Hx;

    // ---- x1 engines: x1 = leaky(h_t @ W1^T + b1), rows d = bk*8 + wid
    if (is_x1){
      int d = bk*8 + wid;
      const float* W1r = W1 + (size_t)d*1024;
      float a4[4] = {0,0,0,0};
      #pragma unroll 4
      for (int it = 0; it < 16; ++it){
        int k = it*64 + klane4;
        float4 wq = *(const float4*)(W1r + k);
        #pragma unroll
        for (int bi = 0; bi < 4; ++bi){
          float4 xv = *(const float4*)(hcur + (size_t)(b4*4 + bi)*1024 + k);
          a4[bi] = fmaf(wq.x,xv.x, fmaf(wq.y,xv.y, fmaf(wq.z,xv.z, fmaf(wq.w,xv.w, a4[bi]))));
        }
      }
      #pragma unroll
      for (int bi = 0; bi < 4; ++bi){
        float v = wred16(a4[bi]);
        if ((tid & 15) == 0){
          v += b1v[d];
          v = (v >= 0.f) ? v : 0.1f*v;
          x1ws[(b4*4 + bi)*256 + d] = v;
        }
      }
      __syncthreads();
      if (tid == 0){
        __threadfence();
        __hip_atomic_fetch_add(flag1 + t, 1, __ATOMIC_ACQ_REL, __HIP_MEMORY_SCOPE_AGENT);
      }
    }

    // ---- head engines: x2 -> out -> softmax -> align  (before their gate partial)
    if (is_head){
      block_wait(flag1 + t, 32);
      {
        int kq = tid & 3;
        const float* x1b = x1ws + hbb*256 + kq*64;
        float a = 0.f;
        #pragma unroll
        for (int i = 0; i < 16; ++i){
          float4 xv = *(const float4*)(x1b + i*4);
          a = fmaf(w2r[i].x,xv.x, fmaf(w2r[i].y,xv.y, fmaf(w2r[i].z,xv.z, fmaf(w2r[i].w,xv.w, a))));
        }
        x2p[tid] = a;  // tid = r*4+kq
      }
      __syncthreads();
      if (tid < 128) x2l[tid] = ftanh(x2p[4*tid] + x2p[4*tid+1] + x2p[4*tid+2] + x2p[4*tid+3]);
      __syncthreads();
      if (half == 1){
        if (tid < 24){
          float s = 0.f;
          const float* wr = Wlin + (size_t)tid*256 + 128;
          #pragma unroll 8
          for (int k = 0; k < 128; ++k) s = fmaf(x2l[k], wr[k], s);
          pout[hbb*32 + tid] = s;
        }
        __syncthreads();
        if (tid == 0){ __threadfence(); st_rel(pf + t*16 + hbb, 1); }
      } else {
        float myp = 0.f;
        if (tid < 24){
          const float* wr = Wlin + (size_t)tid*256;
          #pragma unroll 8
          for (int k = 0; k < 128; ++k) myp = fmaf(x2l[k], wr[k], myp);
        }
        block_wait(pf + t*16 + hbb, 1);
        if (tid < 24) outl[tid] = blin[tid] + myp + pout[hbb*32 + tid];
        __syncthreads();
        if (tid == 0){
          float w8[8]; float mx = -1e30f;
          #pragma unroll
          for (int m = 0; m < 8; ++m){ w8[m] = outl[m]; mx = fmaxf(mx, w8[m]); }
          float sum = 0.f;
          #pragma unroll
          for (int m = 0; m < 8; ++m){ w8[m] = __expf(w8[m] - mx); sum += w8[m]; }
          float inv = 1.0f / sum;
          float cm1 = (float)condlen[hbb] - 1.0f;
          #pragma unroll
          for (int m = 0; m < 8; ++m){
            mixw[m] = w8[m] * inv;
            float dl = sigm(outl[8 + m]) + 0.005f;
            float lc = locws[hbb*8 + m] + dl;
            mixlc[m] = lc;                                   // align uses pre-clamp loc
            locws[hbb*8 + m] = fminf(lc, cm1);               // carried loc is clamped
            mixis[m] = 1.0f / sigm(outl[16 + m]);
          }
        }
        __syncthreads();
        {
          float e = (float)tid;
          float a = 0.f;
          #pragma unroll
          for (int m = 0; m < 8; ++m){
            float df = mixlc[m] - e;
            a += (ftanh((df + 0.5f)*mixis[m]) - ftanh((df - 0.5f)*mixis[m])) * mixw[m];
          }
          a *= 0.5f;
          bool valid = (tid < condlen[hbb]) && (t < outlen[hbb]);
          if (!valid) a = 0.f;
          alws[hbb*512 + tid] = a;
          out[CTXOUT + (size_t)hbb*((size_t)DECx*ENCx) + (size_t)t*ENCx + tid] = a;
        }
        __syncthreads();
        if (tid == 0){ __threadfence(); st_rel(flag2 + t*16 + hbb, 1); }
      }
    }

    // ---- region 1: gate partial for step t+1 (mel(t+1) + h_t parts; ctx part deferred)
    float acc[2][4] = {{0,0,0,0},{0,0,0,0}};
    if (t < DECx - 1){
      const int tt = t + 1;
      #pragma unroll
      for (int it = 0; it < 4; ++it){
        int k = it*64 + klane4;
        float4 wa = *(const float4*)(WihR0 + k), wb = *(const float4*)(WihR1 + k);
        gchunk(acc, wa, wb, mel + (size_t)tt*Dx + k, (size_t)DECx*Dx, b4);
      }
      #pragma unroll 4
      for (int it = 0; it < 16; ++it){
        int k = it*64 + klane4;
        float4 wa = *(const float4*)(WhhR0 + k), wb = *(const float4*)(WhhR1 + k);
        gchunk(acc, wa, wb, hcur + k, 1024, b4);
      }
    }

    // ---- ctx duty (head engines exempt; x1 engines take two slices)
    if (is_x1){
      block_wait(flag2 + t*16 + (bk >> 3), 1);
      ctx_slice(2*bk,     t);
      ctx_slice(2*bk + 1, t);
    } else if (bk >= 64){
      block_wait(flag2 + t*16 + (bk >> 4), 1);
      ctx_slice(bk, t);
    }

    gridbar(bar, gen);   // barrier A: all ctx/nctx published

    // ---- region 2: ctx/nctx part of gates, then LSTM cell update -> h_{t+1}
    if (t < DECx - 1){
      #pragma unroll
      for (int it = 0; it < 4; ++it){
        int k = it*64 + klane4;
        float4 wa = *(const float4*)(WihR0 + 256 + k), wb = *(const float4*)(WihR1 + 256 + k);
        gchunk(acc, wa, wb, ctxws + k, 256, b4);
      }
      #pragma unroll
      for (int it = 0; it < 4; ++it){
        int k = it*64 + klane4;
        float4 wa = *(const float4*)(WihR0 + 512 + k), wb = *(const float4*)(WihR1 + 512 + k);
        gchunk(acc, wa, wb, nctxws + k, 256, b4);
      }
      #pragma unroll
      for (int jj = 0; jj < 2; ++jj)
        #pragma unroll
        for (int bi = 0; bi < 4; ++bi){
          float v = wred16(acc[jj][bi]);
          if ((tid & 15) == 0) g_lds[(jidx0 + jj)*16 + b4*4 + bi] = v;
        }
      __syncthreads();
      if (tid < 64){
        int b = tid & 15, ul = tid >> 4, u = bk*4 + ul;
        float gi = g_lds[( 0 + ul)*16 + b] + bih[u]        + bhh[u];
        float gf = g_lds[( 4 + ul)*16 + b] + bih[1024 + u] + bhh[1024 + u];
        float gg = g_lds[( 8 + ul)*16 + b] + bih[2048 + u] + bhh[2048 + u];
        float go = g_lds[(12 + ul)*16 + b] + bih[3072 + u] + bhh[3072 + u];
        float co = cws[b*1024 + u];
        float c2 = sigm(gf)*co + sigm(gi)*ftanh(gg);
        float h2 = sigm(go)*ftanh(c2);
        cws[b*1024 + u]  = c2;
        hnxt[b*1024 + u] = h2;
      }
    }

    gridbar(bar, gen);   // barrier B: h_{t+1} published
  }
}

extern "C" void kernel_launch(void* const* d_in, const int* in_sizes, int n_in,
                              void* d_out, int out_size, void* d_ws, size_t ws_size,
                              hipStream_t stream)
{
  const float* enc    = (const float*)d_in[0];
  const float* mel    = (const float*)d_in[1];
  // d_in[2] = encoder_lengths (unused by reference)
  const int*   outlen = (const int*)d_in[3];
  const int*   cond   = (const int*)d_in[4];
  const float* Wih    = (const float*)d_in[5];
  const float* Whh    = (const float*)d_in[6];
  const float* bih    = (const float*)d_in[7];
  const float* bhh    = (const float*)d_in[8];
  const float* W1     = (const float*)d_in[9];
  const float* b1v    = (const float*)d_in[10];
  const float* W2     = (const float*)d_in[11];
  const float* Wlin   = (const float*)d_in[12];
  const float* blin   = (const float*)d_in[13];
  float* outp = (float*)d_out;
  float* wsf  = (float*)d_ws;

  hipLaunchKernelGGL(gmm_init, dim3(64), dim3(256), 0, stream, wsf);

  void* args[] = {
    (void*)&enc, (void*)&mel, (void*)&outlen, (void*)&cond,
    (void*)&Wih, (void*)&Whh, (void*)&bih, (void*)&bhh,
    (void*)&W1, (void*)&b1v, (void*)&W2, (void*)&Wlin, (void*)&blin,
    (void*)&outp, (void*)&wsf
  };
  hipLaunchCooperativeKernel((void*)gmm_main, dim3(NBLK), dim3(NTHR), args, 0, stream);
}

// Round 2
// 72398.047 us; speedup vs baseline: 3.7818x; 3.7818x over previous
//
#include <hip/hip_runtime.h>
#include <stdint.h>

#define DEV static __device__ __forceinline__

namespace {
constexpr int Bx = 16, ENCx = 512, DECx = 800, Dx = 256, Hx = 1024;
constexpr int NBLK = 256, NTHR = 512;

// ---- workspace float offsets ----
constexpr int WS_HBUF = 0;                     // 2 * B*H (double-buffered h)
constexpr int WS_CTX  = WS_HBUF + 2*Bx*Hx;     // B*D
constexpr int WS_NCTX = WS_CTX  + Bx*Dx;       // B*D
constexpr int WS_X1   = WS_NCTX + Bx*Dx;       // B*D
constexpr int WS_AL   = WS_X1   + Bx*Dx;       // B*ENC
constexpr int WS_POUT = WS_AL   + Bx*ENCx;     // 16*32
constexpr int WS_FEND = WS_POUT + Bx*32;
// ---- int offsets (relative to wsf + WS_FEND) ----
constexpr int IW_F1   = 0;                     // flag1[DEC]    : x1 done (count to 32)
constexpr int IW_F2   = IW_F1 + DECx;          // flag2[DEC*16] : align[b] done
constexpr int IW_PF   = IW_F2 + DECx*16;       // pf[DEC*16]    : half1 partial done
constexpr int IW_SLOT = ((IW_PF + DECx*16 + 63)/64)*64;  // 256 barrier slots
constexpr int IW_GEN  = IW_SLOT + 256 + 64;    // barrier generation (own line)
constexpr int IW_END  = IW_GEN + 64;
constexpr size_t CTXOUT = (size_t)Bx*DECx*Dx;  // weights output offset

// ---- dynamic LDS float offsets ----
constexpr int LW_G   = 0;                      // [16][1792] gate rows (Wih 768 | Whh 1024)
constexpr int LW_AUX = 16*1792;                // 8192 floats: x1->W1 rows; head->wlinT(3072)+blin(24)
constexpr int LDS_DYN_F = LW_AUX + 8192;       // 36864 floats
constexpr size_t SMEM_BYTES = (size_t)LDS_DYN_F * 4;   // 147456 B
}

DEV float frcp(float x){ return __builtin_amdgcn_rcpf(x); }
DEV float sigm(float x){ return frcp(1.0f + __expf(-x)); }
DEV float ftanh(float x){
  x = fminf(fmaxf(x, -15.0f), 15.0f);
  float e = __expf(2.0f*x);
  return (e - 1.0f) * frcp(e + 1.0f);
}
DEV float wred16(float v){
  v += __shfl_xor(v, 1); v += __shfl_xor(v, 2);
  v += __shfl_xor(v, 4); v += __shfl_xor(v, 8);
  return v;
}
// relaxed agent atomics: poll/communicate through the coherence point, NO cache invalidation
DEV int   ld_rlx(const int* p){ return __hip_atomic_load(p, __ATOMIC_RELAXED, __HIP_MEMORY_SCOPE_AGENT); }
DEV void  st_rlx(int* p, int v){ __hip_atomic_store(p, v, __ATOMIC_RELAXED, __HIP_MEMORY_SCOPE_AGENT); }
DEV float ldf_c(const float* p){ return __hip_atomic_load(p, __ATOMIC_RELAXED, __HIP_MEMORY_SCOPE_AGENT); }
DEV void  stf_c(float* p, float v){ __hip_atomic_store(p, v, __ATOMIC_RELAXED, __HIP_MEMORY_SCOPE_AGENT); }
DEV void fence_acq(){ __builtin_amdgcn_fence(__ATOMIC_ACQUIRE, "agent"); }
DEV void fence_rel(){ __builtin_amdgcn_fence(__ATOMIC_RELEASE, "agent"); }

// flag wait WITHOUT any cache maintenance (consumer reads via coherent atomic loads)
DEV void flag_wait(int* p, int target){
  if (threadIdx.x == 0){
    while (ld_rlx(p) < target) __builtin_amdgcn_s_sleep(1);
  }
  __syncthreads();
}

// slot-based grid barrier; one release + one acquire fence per block per crossing
DEV void gridbar(int* slots, int* genp, unsigned &gen){
  const int next = (int)(gen + 1u);
  __syncthreads();                      // drains vmcnt: block's stores are in L2
  if (threadIdx.x == 0){
    fence_rel();                        // write back my XCD's dirty L2 lines
    st_rlx(slots + blockIdx.x, next);
  }
  if (blockIdx.x == 0 && threadIdx.x < 64){
    int* my = slots + threadIdx.x*4;
    for (;;){
      bool ok = (ld_rlx(my+0) >= next) & (ld_rlx(my+1) >= next) &
                (ld_rlx(my+2) >= next) & (ld_rlx(my+3) >= next);
      if (__ballot(ok) == ~0ull) break;
      __builtin_amdgcn_s_sleep(1);
    }
    if (threadIdx.x == 0) st_rlx(genp, next);
  }
  if (threadIdx.x == 0){
    while (ld_rlx(genp) < next) __builtin_amdgcn_s_sleep(1);
  }
  __syncthreads();
  fence_acq();                          // per-wave invalidate, once per crossing
  gen = (unsigned)next;
}

// one 64-element k-chunk for 2 gate rows x 4 batches
DEV void gchunk(float (&acc)[2][4], float4 wa, float4 wb, const float* xlane, size_t xstride, int b4){
  #pragma unroll
  for (int bi = 0; bi < 4; ++bi){
    float4 xv = *reinterpret_cast<const float4*>(xlane + (size_t)(b4*4 + bi)*xstride);
    acc[0][bi] = fmaf(wa.x,xv.x, fmaf(wa.y,xv.y, fmaf(wa.z,xv.z, fmaf(wa.w,xv.w, acc[0][bi]))));
    acc[1][bi] = fmaf(wb.x,xv.x, fmaf(wb.y,xv.y, fmaf(wb.z,xv.z, fmaf(wb.w,xv.w, acc[1][bi]))));
  }
}

extern "C" __global__ void gmm_init(float* wsf){
  int* wsi = (int*)(wsf + WS_FEND);
  int idx = blockIdx.x*blockDim.x + threadIdx.x;
  for (int k = idx; k < IW_END; k += gridDim.x*blockDim.x) wsi[k] = 0;
}

extern "C" __global__ void __launch_bounds__(NTHR, 1) gmm_main(
    const float* __restrict__ enc, const float* __restrict__ mel,
    const int* __restrict__ outlen, const int* __restrict__ condlen,
    const float* __restrict__ Wih, const float* __restrict__ Whh,
    const float* __restrict__ bih, const float* __restrict__ bhh,
    const float* __restrict__ W1,  const float* __restrict__ b1v,
    const float* __restrict__ W2,  const float* __restrict__ Wlin,
    const float* __restrict__ blin,
    float* __restrict__ out, float* __restrict__ wsf)
{
  const int bk = blockIdx.x, tid = threadIdx.x;
  const int lane = tid & 63;
  const int klane4 = (tid & 15) * 4;
  const int b4 = (tid >> 4) & 3;
  const int wid = tid >> 6;

  int* wsi   = (int*)(wsf + WS_FEND);
  int* flag1 = wsi + IW_F1;
  int* flag2 = wsi + IW_F2;
  int* pf    = wsi + IW_PF;
  int* slots = wsi + IW_SLOT;
  int* genp  = wsi + IW_GEN;
  float* hb0    = wsf + WS_HBUF;
  float* ctxws  = wsf + WS_CTX;
  float* nctxws = wsf + WS_NCTX;
  float* x1ws   = wsf + WS_X1;
  float* alws   = wsf + WS_AL;
  float* pout   = wsf + WS_POUT;

  extern __shared__ float lds[];
  float* lwg = lds + LW_G;     // [16][1792]
  float* lw1 = lds + LW_AUX;   // W1 rows (x1) / wlinT+blin (head)

  __shared__ float g_lds[256];
  __shared__ float bsum[16];
  __shared__ float cl[64];                 // block-private cell state c
  __shared__ float x1l[256];
  __shared__ float x2p[512];
  __shared__ float x2l[128];
  __shared__ float outl[32];
  __shared__ float mixw[8], mixlc[8], mixis[8];
  __shared__ float locl[8];                // block-private loc (head half0)
  __shared__ int   s_cond, s_olen;
  __shared__ float albl[512];
  __shared__ float cpn[2][32][16];

  const int jidx0 = 2*wid;
  const bool is_x1   = (bk < 32);
  const bool is_head = (bk >= 32 && bk < 64);
  const int  hbb  = (bk - 32) >> 1;
  const int  half = (bk - 32) & 1;

  // ---------------- one-time staging ----------------
  // gate rows -> LDS: wave wid loads rows jidx0, jidx0+1
  #pragma unroll
  for (int jj = jidx0; jj <= jidx0 + 1; ++jj){
    const int gj = (jj >> 2)*1024 + bk*4 + (jj & 3);
    float4* dst1 = (float4*)(lwg + jj*1792);
    const float4* s1 = (const float4*)(Wih + (size_t)gj*768);
    for (int i = lane; i < 192; i += 64) dst1[i] = s1[i];
    float4* dst2 = (float4*)(lwg + jj*1792 + 768);
    const float4* s2 = (const float4*)(Whh + (size_t)gj*1024);
    for (int i = lane; i < 256; i += 64) dst2[i] = s2[i];
  }
  if (tid < 16){
    int g = tid >> 2, ul = tid & 3, u = bk*4 + ul;
    bsum[tid] = bih[g*1024 + u] + bhh[g*1024 + u];
  }
  if (is_x1){
    const float4* s = (const float4*)W1 + (size_t)bk*2048;
    float4* d = (float4*)lw1;
    for (int i = tid; i < 2048; i += NTHR) d[i] = s[i];
  }
  float4 w2r[16];
  if (is_head){
    // wlin transposed (k-major) for conflict-free column reads
    for (int i = tid; i < 3072; i += NTHR){
      int r = i >> 7, k = i & 127;
      lw1[k*24 + r] = Wlin[(size_t)r*256 + half*128 + k];
    }
    if (tid < 24) lw1[3072 + tid] = blin[tid];
    if (tid == 0){ s_cond = condlen[hbb]; s_olen = outlen[hbb]; }
    if (half == 0 && tid < 8) locl[tid] = -0.1f;
    int rr = half*128 + (tid >> 2), kq = tid & 3;
    const float* w2row = W2 + (size_t)rr*256 + kq*64;
    #pragma unroll
    for (int i = 0; i < 16; ++i) w2r[i] = *reinterpret_cast<const float4*>(w2row + i*4);
  }
  __syncthreads();

  auto ctx_slice = [&](int s, int t){
    int cb = s >> 4, d0 = (s & 15) * 16;
    int dl = tid & 15, eg = tid >> 4;
    int d = d0 + dl;
    const float* encb = enc + (size_t)cb*ENCx*Dx;
    float ca = 0.f, na = 0.f;
    #pragma unroll
    for (int i = 0; i < 16; ++i){
      int e = eg*16 + i;
      float av = albl[e];
      float nv = albl[(e + 511) & 511];
      float ev = encb[(size_t)e*256 + d];
      ca = fmaf(av, ev, ca);
      na = fmaf(nv, ev, na);
    }
    cpn[0][eg][dl] = ca;
    cpn[1][eg][dl] = na;
    __syncthreads();
    if (tid < 32){
      int z = tid >> 4, dd = tid & 15;
      float sum = 0.f;
      #pragma unroll
      for (int g2 = 0; g2 < 32; ++g2) sum += cpn[z][g2][dd];
      if (z == 0){
        ctxws[cb*256 + d0 + dd] = sum;
        out[(size_t)cb*((size_t)DECx*Dx) + (size_t)t*Dx + d0 + dd] = sum;
      } else {
        nctxws[cb*256 + d0 + dd] = sum;
      }
    }
    __syncthreads();
  };

  unsigned gen = 0;

  // ---------------- prologue: gates t=0 (q=[mel0, 0, enc[:,0,:]], h=0, c=0) ----------------
  {
    float acc[2][4] = {{0,0,0,0},{0,0,0,0}};
    const float* r0 = lwg + jidx0*1792;
    const float* r1 = lwg + (jidx0+1)*1792;
    #pragma unroll
    for (int it = 0; it < 4; ++it){
      int k = it*64 + klane4;
      gchunk(acc, *(const float4*)(r0 + k), *(const float4*)(r1 + k),
             mel + k, (size_t)DECx*Dx, b4);
    }
    #pragma unroll
    for (int it = 0; it < 4; ++it){
      int k = it*64 + klane4;
      gchunk(acc, *(const float4*)(r0 + 512 + k), *(const float4*)(r1 + 512 + k),
             enc + k, (size_t)ENCx*Dx, b4);
    }
    #pragma unroll
    for (int jj = 0; jj < 2; ++jj)
      #pragma unroll
      for (int bi = 0; bi < 4; ++bi){
        float v = wred16(acc[jj][bi]);
        if ((tid & 15) == 0) g_lds[(jidx0 + jj)*16 + b4*4 + bi] = v;
      }
    __syncthreads();
    if (tid < 64){
      int b = tid & 15, ul = tid >> 4, u = bk*4 + ul;
      float gi = g_lds[( 0 + ul)*16 + b] + bsum[ul];
      float gg = g_lds[( 8 + ul)*16 + b] + bsum[8 + ul];
      float go = g_lds[(12 + ul)*16 + b] + bsum[12 + ul];
      float c2 = sigm(gi) * ftanh(gg);
      float h2 = sigm(go) * ftanh(c2);
      cl[b*4 + ul]    = c2;
      hb0[b*1024 + u] = h2;
    }
  }
  gridbar(slots, genp, gen);

  // ---------------- main loop ----------------
  for (int t = 0; t < DECx; ++t){
    const float* hcur = hb0 + (t & 1)*Bx*Hx;
    float*       hnxt = hb0 + ((t + 1) & 1)*Bx*Hx;

    // ---- x1 engines
    if (is_x1){
      int d = bk*8 + wid;
      const float* W1r = lw1 + wid*1024;
      float a4[4] = {0,0,0,0};
      #pragma unroll 4
      for (int it = 0; it < 16; ++it){
        int k = it*64 + klane4;
        float4 wq = *(const float4*)(W1r + k);
        #pragma unroll
        for (int bi = 0; bi < 4; ++bi){
          float4 xv = *(const float4*)(hcur + (size_t)(b4*4 + bi)*1024 + k);
          a4[bi] = fmaf(wq.x,xv.x, fmaf(wq.y,xv.y, fmaf(wq.z,xv.z, fmaf(wq.w,xv.w, a4[bi]))));
        }
      }
      #pragma unroll
      for (int bi = 0; bi < 4; ++bi){
        float v = wred16(a4[bi]);
        if ((tid & 15) == 0){
          v += b1v[d];
          v = (v >= 0.f) ? v : 0.1f*v;
          stf_c(x1ws + (b4*4 + bi)*256 + d, v);          // coherent store -> L3
        }
      }
      __syncthreads();                                    // vmcnt(0): stores at L3
      if (tid == 0)
        __hip_atomic_fetch_add(flag1 + t, 1, __ATOMIC_RELAXED, __HIP_MEMORY_SCOPE_AGENT);
    }

    // ---- head engines (pairs): x2 -> out -> softmax -> align
    if (is_head){
      flag_wait(flag1 + t, 32);
      if (tid < 256) x1l[tid] = ldf_c(x1ws + hbb*256 + tid);   // coherent stage
      __syncthreads();
      {
        int kq = tid & 3;
        const float* x1b = x1l + kq*64;
        float a = 0.f;
        #pragma unroll
        for (int i = 0; i < 16; ++i){
          float4 xv = *(const float4*)(x1b + i*4);
          a = fmaf(w2r[i].x,xv.x, fmaf(w2r[i].y,xv.y, fmaf(w2r[i].z,xv.z, fmaf(w2r[i].w,xv.w, a))));
        }
        x2p[tid] = a;
      }
      __syncthreads();
      if (tid < 128) x2l[tid] = ftanh(x2p[4*tid] + x2p[4*tid+1] + x2p[4*tid+2] + x2p[4*tid+3]);
      __syncthreads();
      if (half == 1){
        if (tid < 24){
          float s = 0.f;
          #pragma unroll 8
          for (int k = 0; k < 128; ++k) s = fmaf(x2l[k], lw1[k*24 + tid], s);
          stf_c(pout + hbb*32 + tid, s);
        }
        __syncthreads();
        if (tid == 0) st_rlx(pf + t*16 + hbb, 1);
      } else {
        float myp = 0.f;
        if (tid < 24){
          #pragma unroll 8
          for (int k = 0; k < 128; ++k) myp = fmaf(x2l[k], lw1[k*24 + tid], myp);
        }
        flag_wait(pf + t*16 + hbb, 1);
        if (tid < 24) outl[tid] = lw1[3072 + tid] + myp + ldf_c(pout + hbb*32 + tid);
        __syncthreads();
        if (tid == 0){
          float w8[8]; float mx = -1e30f;
          #pragma unroll
          for (int m = 0; m < 8; ++m){ w8[m] = outl[m]; mx = fmaxf(mx, w8[m]); }
          float sum = 0.f;
          #pragma unroll
          for (int m = 0; m < 8; ++m){ w8[m] = __expf(w8[m] - mx); sum += w8[m]; }
          float inv = frcp(sum);
          float cm1 = (float)s_cond - 1.0f;
          #pragma unroll
          for (int m = 0; m < 8; ++m){
            mixw[m] = w8[m] * inv;
            float dl = sigm(outl[8 + m]) + 0.005f;
            float lc = locl[m] + dl;
            mixlc[m] = lc;
            locl[m]  = fminf(lc, cm1);
            mixis[m] = 1.0f + __expf(-outl[16 + m]);     // 1/sigm(s)
          }
        }
        __syncthreads();
        {
          float e = (float)tid;
          float a = 0.f;
          #pragma unroll
          for (int m = 0; m < 8; ++m){
            float df = mixlc[m] - e;
            a += (ftanh((df + 0.5f)*mixis[m]) - ftanh((df - 0.5f)*mixis[m])) * mixw[m];
          }
          a *= 0.5f;
          bool valid = (tid < s_cond) && (t < s_olen);
          if (!valid) a = 0.f;
          stf_c(alws + hbb*512 + tid, a);                 // coherent publish
          out[CTXOUT + (size_t)hbb*((size_t)DECx*ENCx) + (size_t)t*ENCx + tid] = a;
        }
        __syncthreads();                                   // vmcnt(0): alws at L3
        if (tid == 0) st_rlx(flag2 + t*16 + hbb, 1);
      }
    }

    // ---- region 1: gate partial for t+1 (mel + Whh*h; ctx part deferred)
    float acc[2][4] = {{0,0,0,0},{0,0,0,0}};
    if (t < DECx - 1){
      const int tt = t + 1;
      const float* r0 = lwg + jidx0*1792;
      const float* r1 = lwg + (jidx0+1)*1792;
      #pragma unroll
      for (int it = 0; it < 4; ++it){
        int k = it*64 + klane4;
        gchunk(acc, *(const float4*)(r0 + k), *(const float4*)(r1 + k),
               mel + (size_t)tt*Dx + k, (size_t)DECx*Dx, b4);
      }
      #pragma unroll 4
      for (int it = 0; it < 16; ++it){
        int k = it*64 + klane4;
        gchunk(acc, *(const float4*)(r0 + 768 + k), *(const float4*)(r1 + 768 + k),
               hcur + k, 1024, b4);
      }
    }

    // ---- ctx duty (head exempt; x1 blocks take two slices)
    if (!is_head){
      int cb = is_x1 ? (bk >> 3) : (bk >> 4);
      flag_wait(flag2 + t*16 + cb, 1);
      albl[tid] = ldf_c(alws + cb*512 + tid);              // coherent stage
      __syncthreads();
      if (is_x1){ ctx_slice(2*bk, t); ctx_slice(2*bk + 1, t); }
      else      { ctx_slice(bk, t); }
    }

    gridbar(slots, genp, gen);   // barrier A: ctx/nctx published (fence-based)

    // ---- region 2: ctx/nctx gate part + LSTM cell -> h_{t+1}
    if (t < DECx - 1){
      const float* r0 = lwg + jidx0*1792;
      const float* r1 = lwg + (jidx0+1)*1792;
      #pragma unroll
      for (int it = 0; it < 4; ++it){
        int k = it*64 + klane4;
        gchunk(acc, *(const float4*)(r0 + 256 + k), *(const float4*)(r1 + 256 + k),
               ctxws + k, 256, b4);
      }
      #pragma unroll
      for (int it = 0; it < 4; ++it){
        int k = it*64 + klane4;
        gchunk(acc, *(const float4*)(r0 + 512 + k), *(const float4*)(r1 + 512 + k),
               nctxws + k, 256, b4);
      }
      #pragma unroll
      for (int jj = 0; jj < 2; ++jj)
        #pragma unroll
        for (int bi = 0; bi < 4; ++bi){
          float v = wred16(acc[jj][bi]);
          if ((tid & 15) == 0) g_lds[(jidx0 + jj)*16 + b4*4 + bi] = v;
        }
      __syncthreads();
      if (tid < 64){
        int b = tid & 15, ul = tid >> 4, u = bk*4 + ul;
        float gi = g_lds[( 0 + ul)*16 + b] + bsum[ul];
        float gf = g_lds[( 4 + ul)*16 + b] + bsum[4 + ul];
        float gg = g_lds[( 8 + ul)*16 + b] + bsum[8 + ul];
        float go = g_lds[(12 + ul)*16 + b] + bsum[12 + ul];
        float co = cl[b*4 + ul];
        float c2 = sigm(gf)*co + sigm(gi)*ftanh(gg);
        float h2 = sigm(go)*ftanh(c2);
        cl[b*4 + ul]     = c2;
        hnxt[b*1024 + u] = h2;
      }
    }

    gridbar(slots, genp, gen);   // barrier B: h_{t+1} published (fence-based)
  }
}

extern "C" void kernel_launch(void* const* d_in, const int* in_sizes, int n_in,
                              void* d_out, int out_size, void* d_ws, size_t ws_size,
                              hipStream_t stream)
{
  const float* enc    = (const float*)d_in[0];
  const float* mel    = (const float*)d_in[1];
  const int*   outlen = (const int*)d_in[3];
  const int*   cond   = (const int*)d_in[4];
  const float* Wih    = (const float*)d_in[5];
  const float* Whh    = (const float*)d_in[6];
  const float* bih    = (const float*)d_in[7];
  const float* bhh    = (const float*)d_in[8];
  const float* W1     = (const float*)d_in[9];
  const float* b1v    = (const float*)d_in[10];
  const float* W2     = (const float*)d_in[11];
  const float* Wlin   = (const float*)d_in[12];
  const float* blin   = (const float*)d_in[13];
  float* outp = (float*)d_out;
  float* wsf  = (float*)d_ws;

  (void)hipFuncSetAttribute((const void*)gmm_main,
                            hipFuncAttributeMaxDynamicSharedMemorySize,
                            (int)SMEM_BYTES);

  hipLaunchKernelGGL(gmm_init, dim3(64), dim3(256), 0, stream, wsf);

  void* args[] = {
    (void*)&enc, (void*)&mel, (void*)&outlen, (void*)&cond,
    (void*)&Wih, (void*)&Whh, (void*)&bih, (void*)&bhh,
    (void*)&W1, (void*)&b1v, (void*)&W2, (void*)&Wlin, (void*)&blin,
    (void*)&outp, (void*)&wsf
  };
  hipLaunchCooperativeKernel((void*)gmm_main, dim3(NBLK), dim3(NTHR),
                             args, SMEM_BYTES, stream);
}

// Round 3
// 62925.525 us; speedup vs baseline: 4.3511x; 1.1505x over previous
//
#include <hip/hip_runtime.h>
#include <stdint.h>

#define DEV static __device__ __forceinline__

namespace {
constexpr int Bx = 16, ENCx = 512, DECx = 800, Dx = 256, Hx = 1024;
constexpr int NBLK = 256, NTHR = 512;

// ---- workspace float offsets ----
constexpr int WS_HBUF = 0;                     // 2 * B*H (double-buffered h)
constexpr int WS_CTX  = WS_HBUF + 2*Bx*Hx;     // B*D
constexpr int WS_NCTX = WS_CTX  + Bx*Dx;       // B*D
constexpr int WS_X1   = WS_NCTX + Bx*Dx;       // B*D
constexpr int WS_AL   = WS_X1   + Bx*Dx;       // B*ENC
constexpr int WS_POUT = WS_AL   + Bx*ENCx;     // 16*32
constexpr int WS_FEND = WS_POUT + Bx*32;
// ---- int offsets (relative to wsf + WS_FEND) ----
constexpr int IW_F1   = 0;                     // flag1[DEC]    : x1 done (count to 32)
constexpr int IW_F2   = IW_F1 + DECx;          // flag2[DEC*16] : align[b] done
constexpr int IW_PF   = IW_F2 + DECx*16;       // pf[DEC*16]    : half1 partial done
constexpr int IW_SLOT = ((IW_PF + DECx*16 + 63)/64)*64;  // 256 barrier slots
constexpr int IW_GEN  = IW_SLOT + 256 + 64;    // barrier generation (own line)
constexpr int IW_END  = IW_GEN + 64;
constexpr size_t CTXOUT = (size_t)Bx*DECx*Dx;  // weights output offset

// ---- dynamic LDS float offsets ----
constexpr int LW_H   = 0;         // 16384: h[16][1024]; reused as ctx[16][256]|nctx[16][256] in region2
constexpr int LW_WHH = 16384;     // 16384: Whh rows [16][1024]
constexpr int LW_AUX = 32768;     // 3104 : head wlinT(128*24) + blin(24)
constexpr int LDS_DYN_F = LW_AUX + 3104;
constexpr size_t SMEM_BYTES = (size_t)LDS_DYN_F * 4;   // 143,488 B
}

DEV float frcp(float x){ return __builtin_amdgcn_rcpf(x); }
DEV float sigm(float x){ return frcp(1.0f + __expf(-x)); }
DEV float ftanh(float x){
  x = fminf(fmaxf(x, -15.0f), 15.0f);
  float e = __expf(2.0f*x);
  return (e - 1.0f) * frcp(e + 1.0f);
}
DEV float wred16(float v){
  v += __shfl_xor(v, 1); v += __shfl_xor(v, 2);
  v += __shfl_xor(v, 4); v += __shfl_xor(v, 8);
  return v;
}
// ALL mutable cross-block data goes through these (sc0 sc1: bypass L1/L2, hit coherence point).
// No fences anywhere -> read-only data stays L1/L2-resident forever.
DEV int   ld_rlx(const int* p){ return __hip_atomic_load(p, __ATOMIC_RELAXED, __HIP_MEMORY_SCOPE_AGENT); }
DEV void  st_rlx(int* p, int v){ __hip_atomic_store(p, v, __ATOMIC_RELAXED, __HIP_MEMORY_SCOPE_AGENT); }
DEV float ldf_c(const float* p){ return __hip_atomic_load(p, __ATOMIC_RELAXED, __HIP_MEMORY_SCOPE_AGENT); }
DEV void  stf_c(float* p, float v){ __hip_atomic_store(p, v, __ATOMIC_RELAXED, __HIP_MEMORY_SCOPE_AGENT); }
DEV float2 ldf2_c(const float* p){
  unsigned long long u = __hip_atomic_load((const unsigned long long*)p,
                                           __ATOMIC_RELAXED, __HIP_MEMORY_SCOPE_AGENT);
  return __builtin_bit_cast(float2, u);
}
DEV void cbar(){ asm volatile("" ::: "memory"); }   // compiler-only ordering

DEV void flag_wait(int* p, int target){
  if (threadIdx.x == 0){
    while (ld_rlx(p) < target) __builtin_amdgcn_s_sleep(1);
  }
  __syncthreads();
  cbar();
}

// fence-free grid barrier. Release = the s_waitcnt vmcnt(0) __syncthreads() emits
// (sc1 data stores complete at the coherence point before the slot store issues).
DEV void gridbar(int* slots, int* genp, unsigned &gen){
  const int next = (int)(gen + 1u);
  __syncthreads();                       // drains vmcnt: all sc1 stores at L3
  if (threadIdx.x == 0) st_rlx(slots + blockIdx.x, next);
  if (blockIdx.x == 0 && threadIdx.x < 64){
    int* my = slots + threadIdx.x*4;
    for (;;){
      bool ok = (ld_rlx(my+0) >= next) & (ld_rlx(my+1) >= next) &
                (ld_rlx(my+2) >= next) & (ld_rlx(my+3) >= next);
      if (__ballot(ok) == ~0ull) break;
      __builtin_amdgcn_s_sleep(1);
    }
    if (threadIdx.x == 0) st_rlx(genp, next);
  }
  if (threadIdx.x == 0){
    while (ld_rlx(genp) < next) __builtin_amdgcn_s_sleep(1);
  }
  __syncthreads();
  cbar();
  gen = (unsigned)next;
}

// one 64-element k-chunk for 2 gate rows x 4 batches (x may be LDS or global; inlined)
DEV void gchunk(float (&acc)[2][4], float4 wa, float4 wb, const float* xlane, size_t xstride, int b4){
  #pragma unroll
  for (int bi = 0; bi < 4; ++bi){
    float4 xv = *reinterpret_cast<const float4*>(xlane + (size_t)(b4*4 + bi)*xstride);
    acc[0][bi] = fmaf(wa.x,xv.x, fmaf(wa.y,xv.y, fmaf(wa.z,xv.z, fmaf(wa.w,xv.w, acc[0][bi]))));
    acc[1][bi] = fmaf(wb.x,xv.x, fmaf(wb.y,xv.y, fmaf(wb.z,xv.z, fmaf(wb.w,xv.w, acc[1][bi]))));
  }
}

extern "C" __global__ void gmm_init(float* wsf){
  int* wsi = (int*)(wsf + WS_FEND);
  int idx = blockIdx.x*blockDim.x + threadIdx.x;
  for (int k = idx; k < IW_END; k += gridDim.x*blockDim.x) wsi[k] = 0;
}

extern "C" __global__ void __launch_bounds__(NTHR, 1) gmm_main(
    const float* __restrict__ enc, const float* __restrict__ mel,
    const int* __restrict__ outlen, const int* __restrict__ condlen,
    const float* __restrict__ Wih, const float* __restrict__ Whh,
    const float* __restrict__ bih, const float* __restrict__ bhh,
    const float* __restrict__ W1,  const float* __restrict__ b1v,
    const float* __restrict__ W2,  const float* __restrict__ Wlin,
    const float* __restrict__ blin,
    float* __restrict__ out, float* __restrict__ wsf)
{
  const int bk = blockIdx.x, tid = threadIdx.x;
  const int lane = tid & 63;
  const int klane4 = (tid & 15) * 4;
  const int b4 = (tid >> 4) & 3;
  const int wid = tid >> 6;

  int* wsi   = (int*)(wsf + WS_FEND);
  int* flag1 = wsi + IW_F1;
  int* flag2 = wsi + IW_F2;
  int* pf    = wsi + IW_PF;
  int* slots = wsi + IW_SLOT;
  int* genp  = wsi + IW_GEN;
  float* hb0    = wsf + WS_HBUF;
  float* ctxws  = wsf + WS_CTX;
  float* nctxws = wsf + WS_NCTX;
  float* x1ws   = wsf + WS_X1;
  float* alws   = wsf + WS_AL;
  float* pout   = wsf + WS_POUT;

  extern __shared__ float lds[];
  float* lh   = lds + LW_H;     // h stage / ctx|nctx stage
  float* lwhh = lds + LW_WHH;   // Whh rows
  float* laux = lds + LW_AUX;   // head: wlinT + blin

  __shared__ float g_lds[256];
  __shared__ float bsum[16];
  __shared__ float cl[64];
  __shared__ float x1l[256];
  __shared__ float x2p[512];
  __shared__ float x2l[128];
  __shared__ float outl[32];
  __shared__ float mixw[8], mixlc[8], mixis[8];
  __shared__ float locl[8];
  __shared__ int   s_cond, s_olen;
  __shared__ float albl[512];
  __shared__ float cpn[2][32][16];

  const int jidx0 = 2*wid;
  const int j0 = (jidx0 >> 2)*1024 + bk*4 + (jidx0 & 3);
  const int j1 = ((jidx0+1) >> 2)*1024 + bk*4 + ((jidx0+1) & 3);
  const float* WihR0 = Wih + (size_t)j0*768;   // global, read-only -> L2-resident
  const float* WihR1 = Wih + (size_t)j1*768;

  const bool is_x1   = (bk < 32);
  const bool is_head = (bk >= 32 && bk < 64);
  const int  hbb  = (bk - 32) >> 1;
  const int  half = (bk - 32) & 1;

  // ---------------- one-time staging ----------------
  // Whh rows -> LDS (wave wid loads its 2 rows)
  #pragma unroll
  for (int jj = jidx0; jj <= jidx0 + 1; ++jj){
    const int gj = (jj >> 2)*1024 + bk*4 + (jj & 3);
    float4* dst = (float4*)(lwhh + jj*1024);
    const float4* s = (const float4*)(Whh + (size_t)gj*1024);
    for (int i = lane; i < 256; i += 64) dst[i] = s[i];
  }
  if (tid < 16){
    int g = tid >> 2, ul = tid & 3, u = bk*4 + ul;
    bsum[tid] = bih[g*1024 + u] + bhh[g*1024 + u];
  }
  float4 w2r[16];
  if (is_head){
    for (int i = tid; i < 3072; i += NTHR){
      int r = i >> 7, k = i & 127;
      laux[k*24 + r] = Wlin[(size_t)r*256 + half*128 + k];
    }
    if (tid < 24) laux[3072 + tid] = blin[tid];
    if (tid == 0){ s_cond = condlen[hbb]; s_olen = outlen[hbb]; }
    if (half == 0 && tid < 8) locl[tid] = -0.1f;
    int rr = half*128 + (tid >> 2), kq = tid & 3;
    const float* w2row = W2 + (size_t)rr*256 + kq*64;
    #pragma unroll
    for (int i = 0; i < 16; ++i) w2r[i] = *reinterpret_cast<const float4*>(w2row + i*4);
  }
  __syncthreads();

  auto ctx_slice = [&](int s, int t){
    int cb = s >> 4, d0 = (s & 15) * 16;
    int dl = tid & 15, eg = tid >> 4;
    int d = d0 + dl;
    const float* encb = enc + (size_t)cb*ENCx*Dx;
    float ca = 0.f, na = 0.f;
    #pragma unroll
    for (int i = 0; i < 16; ++i){
      int e = eg*16 + i;
      float av = albl[e];
      float nv = albl[(e + 511) & 511];
      float ev = encb[(size_t)e*256 + d];
      ca = fmaf(av, ev, ca);
      na = fmaf(nv, ev, na);
    }
    cpn[0][eg][dl] = ca;
    cpn[1][eg][dl] = na;
    __syncthreads();
    if (tid < 32){
      int z = tid >> 4, dd = tid & 15;
      float sum = 0.f;
      #pragma unroll
      for (int g2 = 0; g2 < 32; ++g2) sum += cpn[z][g2][dd];
      if (z == 0){
        stf_c(ctxws + cb*256 + d0 + dd, sum);
        out[(size_t)cb*((size_t)DECx*Dx) + (size_t)t*Dx + d0 + dd] = sum;
      } else {
        stf_c(nctxws + cb*256 + d0 + dd, sum);
      }
    }
    __syncthreads();
  };

  unsigned gen = 0;

  // ---------------- prologue: gates t=0 (q=[mel0, 0, enc[:,0,:]], h=0, c=0) ----------------
  {
    float acc[2][4] = {{0,0,0,0},{0,0,0,0}};
    #pragma unroll
    for (int it = 0; it < 4; ++it){
      int k = it*64 + klane4;
      gchunk(acc, *(const float4*)(WihR0 + k), *(const float4*)(WihR1 + k),
             mel + k, (size_t)DECx*Dx, b4);
    }
    #pragma unroll
    for (int it = 0; it < 4; ++it){
      int k = it*64 + klane4;
      gchunk(acc, *(const float4*)(WihR0 + 512 + k), *(const float4*)(WihR1 + 512 + k),
             enc + k, (size_t)ENCx*Dx, b4);
    }
    #pragma unroll
    for (int jj = 0; jj < 2; ++jj)
      #pragma unroll
      for (int bi = 0; bi < 4; ++bi){
        float v = wred16(acc[jj][bi]);
        if ((tid & 15) == 0) g_lds[(jidx0 + jj)*16 + b4*4 + bi] = v;
      }
    __syncthreads();
    if (tid < 64){
      int b = tid & 15, ul = tid >> 4, u = bk*4 + ul;
      float gi = g_lds[( 0 + ul)*16 + b] + bsum[ul];
      float gg = g_lds[( 8 + ul)*16 + b] + bsum[8 + ul];
      float go = g_lds[(12 + ul)*16 + b] + bsum[12 + ul];
      float c2 = sigm(gi) * ftanh(gg);
      float h2 = sigm(go) * ftanh(c2);
      cl[b*4 + ul] = c2;
      stf_c(hb0 + b*1024 + u, h2);
    }
  }
  gridbar(slots, genp, gen);

  // ---------------- main loop ----------------
  for (int t = 0; t < DECx; ++t){
    // ---- stage h_t into LDS (dedupe the 8-wave redundancy; sc1 loads = fresh)
    {
      const float* hsrc = hb0 + (t & 1)*Bx*Hx;
      float2* dst = (float2*)lh;
      #pragma unroll 4
      for (int i = tid; i < 8192; i += NTHR) dst[i] = ldf2_c(hsrc + 2*i);
    }
    __syncthreads();

    // ---- x1 engines (h from LDS, W1 from L2)
    if (is_x1){
      int d = bk*8 + wid;
      const float* W1r = W1 + (size_t)d*1024;
      float a4[4] = {0,0,0,0};
      #pragma unroll 4
      for (int it = 0; it < 16; ++it){
        int k = it*64 + klane4;
        float4 wq = *(const float4*)(W1r + k);
        #pragma unroll
        for (int bi = 0; bi < 4; ++bi){
          float4 xv = *(const float4*)(lh + (size_t)(b4*4 + bi)*1024 + k);
          a4[bi] = fmaf(wq.x,xv.x, fmaf(wq.y,xv.y, fmaf(wq.z,xv.z, fmaf(wq.w,xv.w, a4[bi]))));
        }
      }
      #pragma unroll
      for (int bi = 0; bi < 4; ++bi){
        float v = wred16(a4[bi]);
        if ((tid & 15) == 0){
          v += b1v[d];
          v = (v >= 0.f) ? v : 0.1f*v;
          stf_c(x1ws + (b4*4 + bi)*256 + d, v);
        }
      }
      __syncthreads();                       // vmcnt(0): x1 stores at coherence point
      if (tid == 0)
        __hip_atomic_fetch_add(flag1 + t, 1, __ATOMIC_RELAXED, __HIP_MEMORY_SCOPE_AGENT);
    }

    // ---- head engines (pairs): x2 -> out -> softmax -> align
    if (is_head){
      flag_wait(flag1 + t, 32);
      if (tid < 256) x1l[tid] = ldf_c(x1ws + hbb*256 + tid);
      __syncthreads();
      {
        int kq = tid & 3;
        const float* x1b = x1l + kq*64;
        float a = 0.f;
        #pragma unroll
        for (int i = 0; i < 16; ++i){
          float4 xv = *(const float4*)(x1b + i*4);
          a = fmaf(w2r[i].x,xv.x, fmaf(w2r[i].y,xv.y, fmaf(w2r[i].z,xv.z, fmaf(w2r[i].w,xv.w, a))));
        }
        x2p[tid] = a;
      }
      __syncthreads();
      if (tid < 128) x2l[tid] = ftanh(x2p[4*tid] + x2p[4*tid+1] + x2p[4*tid+2] + x2p[4*tid+3]);
      __syncthreads();
      if (half == 1){
        if (tid < 24){
          float s = 0.f;
          #pragma unroll 8
          for (int k = 0; k < 128; ++k) s = fmaf(x2l[k], laux[k*24 + tid], s);
          stf_c(pout + hbb*32 + tid, s);
        }
        __syncthreads();
        if (tid == 0) st_rlx(pf + t*16 + hbb, 1);
      } else {
        float myp = 0.f;
        if (tid < 24){
          #pragma unroll 8
          for (int k = 0; k < 128; ++k) myp = fmaf(x2l[k], laux[k*24 + tid], myp);
        }
        flag_wait(pf + t*16 + hbb, 1);
        if (tid < 24) outl[tid] = laux[3072 + tid] + myp + ldf_c(pout + hbb*32 + tid);
        __syncthreads();
        if (tid == 0){
          float w8[8]; float mx = -1e30f;
          #pragma unroll
          for (int m = 0; m < 8; ++m){ w8[m] = outl[m]; mx = fmaxf(mx, w8[m]); }
          float sum = 0.f;
          #pragma unroll
          for (int m = 0; m < 8; ++m){ w8[m] = __expf(w8[m] - mx); sum += w8[m]; }
          float inv = frcp(sum);
          float cm1 = (float)s_cond - 1.0f;
          #pragma unroll
          for (int m = 0; m < 8; ++m){
            mixw[m] = w8[m] * inv;
            float dl = sigm(outl[8 + m]) + 0.005f;
            float lc = locl[m] + dl;
            mixlc[m] = lc;
            locl[m]  = fminf(lc, cm1);
            mixis[m] = 1.0f + __expf(-outl[16 + m]);
          }
        }
        __syncthreads();
        {
          float e = (float)tid;
          float a = 0.f;
          #pragma unroll
          for (int m = 0; m < 8; ++m){
            float df = mixlc[m] - e;
            a += (ftanh((df + 0.5f)*mixis[m]) - ftanh((df - 0.5f)*mixis[m])) * mixw[m];
          }
          a *= 0.5f;
          bool valid = (tid < s_cond) && (t < s_olen);
          if (!valid) a = 0.f;
          stf_c(alws + hbb*512 + tid, a);
          out[CTXOUT + (size_t)hbb*((size_t)DECx*ENCx) + (size_t)t*ENCx + tid] = a;
        }
        __syncthreads();                     // vmcnt(0): align at coherence point
        if (tid == 0) st_rlx(flag2 + t*16 + hbb, 1);
      }
    }

    // ---- region 1: gate partial for t+1 (Wih-mel from L2; Whh from LDS; h from LDS)
    float acc[2][4] = {{0,0,0,0},{0,0,0,0}};
    if (t < DECx - 1){
      const int tt = t + 1;
      #pragma unroll
      for (int it = 0; it < 4; ++it){
        int k = it*64 + klane4;
        gchunk(acc, *(const float4*)(WihR0 + k), *(const float4*)(WihR1 + k),
               mel + (size_t)tt*Dx + k, (size_t)DECx*Dx, b4);
      }
      #pragma unroll 4
      for (int it = 0; it < 16; ++it){
        int k = it*64 + klane4;
        gchunk(acc, *(const float4*)(lwhh + jidx0*1024 + k), *(const float4*)(lwhh + (jidx0+1)*1024 + k),
               lh + k, 1024, b4);
      }
    }

    // ---- ctx duty (head exempt; x1 blocks take two slices)
    if (!is_head){
      int cb = is_x1 ? (bk >> 3) : (bk >> 4);
      flag_wait(flag2 + t*16 + cb, 1);
      albl[tid] = ldf_c(alws + cb*512 + tid);
      __syncthreads();
      if (is_x1){ ctx_slice(2*bk, t); ctx_slice(2*bk + 1, t); }
      else      { ctx_slice(bk, t); }
    }

    gridbar(slots, genp, gen);   // barrier A: ctx/nctx published

    // ---- region 2: ctx/nctx gate part + LSTM cell -> h_{t+1}
    if (t < DECx - 1){
      // stage ctx|nctx into lh (h_t no longer needed)
      {
        float2* d0 = (float2*)lh;
        float2* d1 = (float2*)(lh + 4096);
        #pragma unroll 2
        for (int i = tid; i < 2048; i += NTHR) d0[i] = ldf2_c(ctxws + 2*i);
        #pragma unroll 2
        for (int i = tid; i < 2048; i += NTHR) d1[i] = ldf2_c(nctxws + 2*i);
      }
      __syncthreads();
      #pragma unroll
      for (int it = 0; it < 4; ++it){
        int k = it*64 + klane4;
        gchunk(acc, *(const float4*)(WihR0 + 256 + k), *(const float4*)(WihR1 + 256 + k),
               lh + k, 256, b4);
      }
      #pragma unroll
      for (int it = 0; it < 4; ++it){
        int k = it*64 + klane4;
        gchunk(acc, *(const float4*)(WihR0 + 512 + k), *(const float4*)(WihR1 + 512 + k),
               lh + 4096 + k, 256, b4);
      }
      #pragma unroll
      for (int jj = 0; jj < 2; ++jj)
        #pragma unroll
        for (int bi = 0; bi < 4; ++bi){
          float v = wred16(acc[jj][bi]);
          if ((tid & 15) == 0) g_lds[(jidx0 + jj)*16 + b4*4 + bi] = v;
        }
      __syncthreads();
      if (tid < 64){
        int b = tid & 15, ul = tid >> 4, u = bk*4 + ul;
        float gi = g_lds[( 0 + ul)*16 + b] + bsum[ul];
        float gf = g_lds[( 4 + ul)*16 + b] + bsum[4 + ul];
        float gg = g_lds[( 8 + ul)*16 + b] + bsum[8 + ul];
        float go = g_lds[(12 + ul)*16 + b] + bsum[12 + ul];
        float co = cl[b*4 + ul];
        float c2 = sigm(gf)*co + sigm(gi)*ftanh(gg);
        float h2 = sigm(go)*ftanh(c2);
        cl[b*4 + ul] = c2;
        stf_c(hb0 + ((t + 1) & 1)*Bx*Hx + b*1024 + u, h2);
      }
    }

    gridbar(slots, genp, gen);   // barrier B: h_{t+1} published
  }
}

extern "C" void kernel_launch(void* const* d_in, const int* in_sizes, int n_in,
                              void* d_out, int out_size, void* d_ws, size_t ws_size,
                              hipStream_t stream)
{
  const float* enc    = (const float*)d_in[0];
  const float* mel    = (const float*)d_in[1];
  const int*   outlen = (const int*)d_in[3];
  const int*   cond   = (const int*)d_in[4];
  const float* Wih    = (const float*)d_in[5];
  const float* Whh    = (const float*)d_in[6];
  const float* bih    = (const float*)d_in[7];
  const float* bhh    = (const float*)d_in[8];
  const float* W1     = (const float*)d_in[9];
  const float* b1v    = (const float*)d_in[10];
  const float* W2     = (const float*)d_in[11];
  const float* Wlin   = (const float*)d_in[12];
  const float* blin   = (const float*)d_in[13];
  float* outp = (float*)d_out;
  float* wsf  = (float*)d_ws;

  (void)hipFuncSetAttribute((const void*)gmm_main,
                            hipFuncAttributeMaxDynamicSharedMemorySize,
                            (int)SMEM_BYTES);

  hipLaunchKernelGGL(gmm_init, dim3(64), dim3(256), 0, stream, wsf);

  void* args[] = {
    (void*)&enc, (void*)&mel, (void*)&outlen, (void*)&cond,
    (void*)&Wih, (void*)&Whh, (void*)&bih, (void*)&bhh,
    (void*)&W1, (void*)&b1v, (void*)&W2, (void*)&Wlin, (void*)&blin,
    (void*)&outp, (void*)&wsf
  };
  hipLaunchCooperativeKernel((void*)gmm_main, dim3(NBLK), dim3(NTHR),
                             args, SMEM_BYTES, stream);
}